// Round 8
// baseline (109.183 us; speedup 1.0000x reference)
//
#include <hip/hip_runtime.h>

#define KS   13
#define HALF 6
#define TX   64
#define TY   64
#define NT   4           // tiles per block, stacked along y (pipelined prefetch)
#define S_H  76
#define S_P  84          // pitch (floats): rows shift 21 granule-slots -> even spread
#define NG   20          // staged float4 granules/row (80 floats: 8 halo + 64 + 8)
#define NSTG (S_H * NG)  // 1520 staging tasks
#define IMG_H 1024
#define IMG_W 1024

__device__ __forceinline__ int reflect_idx(int i, int n) {
    if (i < 0) i = -i;
    if (i >= n) i = 2 * n - 2 - i;
    return i;
}

// H task (r, qq): outputs rel cols 16qq..16qq+15 from staged floats 16qq+2..16qq+29.
__device__ __forceinline__ void h_read_compute(const float (*s)[S_P], const float* g,
                                               int r, int qq, float* acc) {
    const int base = 16 * qq;
    float w[32];
    #pragma unroll
    for (int k = 0; k < 8; ++k) {
        float4 v = *reinterpret_cast<const float4*>(&s[r][base + 4 * k]);
        w[4*k+0] = v.x; w[4*k+1] = v.y; w[4*k+2] = v.z; w[4*k+3] = v.w;
    }
    #pragma unroll
    for (int u = 0; u < 16; ++u) acc[u] = 0.0f;
    #pragma unroll
    for (int j = 0; j < KS; ++j) {
        #pragma unroll
        for (int u = 0; u < 16; ++u)
            acc[u] += g[j] * w[u + 2 + j];
    }
}

__device__ __forceinline__ void h_write(float (*s)[S_P], int r, int qq, const float* acc) {
    const int base = 8 + 16 * qq;   // H row r -> s[r][8..71]
    #pragma unroll
    for (int k = 0; k < 4; ++k)
        *reinterpret_cast<float4*>(&s[r][base + 4 * k]) =
            make_float4(acc[4*k], acc[4*k+1], acc[4*k+2], acc[4*k+3]);
}

// Load one staging slot for the tile whose top output row is oyt.
__device__ __forceinline__ float4 stage_load(const float* __restrict__ xin,
                                             int oyt, int r, int gc0, bool interior) {
    int gr = reflect_idx(oyt + r - HALF, IMG_H);
    const float* row = xin + (size_t)gr * IMG_W;
    float4 v;
    if (interior) {
        v = *reinterpret_cast<const float4*>(row + gc0);
    } else {
        v.x = row[reflect_idx(gc0 + 0, IMG_W)];
        v.y = row[reflect_idx(gc0 + 1, IMG_W)];
        v.z = row[reflect_idx(gc0 + 2, IMG_W)];
        v.w = row[reflect_idx(gc0 + 3, IMG_W)];
    }
    return v;
}

// No min-waves bound: (256,6) capped VGPRs at 40 -> 543 MB scratch spill (R2).
__global__ __launch_bounds__(256) void gauss_blur_fused(
    const float* __restrict__ x, const float* __restrict__ k2d,
    float* __restrict__ out)
{
    __shared__ float s[S_H][S_P];   // 25536 B

    const int tid = threadIdx.x;
    const int bx  = blockIdx.x;
    const int ox  = bx * TX;
    const int oy0 = blockIdx.y * (TY * NT);
    const int img = blockIdx.z;

    const float* xin = x + (size_t)img * IMG_H * IMG_W;
    float*       o   = out + (size_t)img * IMG_H * IMG_W;

    float g[KS];
    {
        float c   = k2d[HALF * KS + HALF];
        float inv = 1.0f / sqrtf(c);
        #pragma unroll
        for (int j = 0; j < KS; ++j) g[j] = k2d[j * KS + HALF] * inv;
    }

    const bool interior = (bx > 0) && (bx < (IMG_W / TX) - 1);

    // Per-thread staging slots k=0..5: idx_k = tid + 256k  (k=5 valid iff tid<240)
    const int i0 = tid,            r0 = i0 / NG, c40 = i0 - r0 * NG;
    const int i1 = tid + 256,      r1 = i1 / NG, c41 = i1 - r1 * NG;
    const int i2 = tid + 512,      r2 = i2 / NG, c42 = i2 - r2 * NG;
    const int i3 = tid + 768,      r3 = i3 / NG, c43 = i3 - r3 * NG;
    const int i4 = tid + 1024,     r4 = i4 / NG, c44 = i4 - r4 * NG;
    const int i5 = tid + 1280,     r5 = (i5 < NSTG) ? i5 / NG : 0,
              c45 = (i5 < NSTG) ? i5 - r5 * NG : 0;
    const bool has5 = (i5 < NSTG);
    const int gc0_0 = ox - 8 + c40 * 4, gc0_1 = ox - 8 + c41 * 4,
              gc0_2 = ox - 8 + c42 * 4, gc0_3 = ox - 8 + c43 * 4,
              gc0_4 = ox - 8 + c44 * 4, gc0_5 = ox - 8 + c45 * 4;

    // prefetch tile 0 into registers (named: no runtime indexing -> no scratch)
    float4 st0 = stage_load(xin, oy0, r0, gc0_0, interior);
    float4 st1 = stage_load(xin, oy0, r1, gc0_1, interior);
    float4 st2 = stage_load(xin, oy0, r2, gc0_2, interior);
    float4 st3 = stage_load(xin, oy0, r3, gc0_3, interior);
    float4 st4 = stage_load(xin, oy0, r4, gc0_4, interior);
    float4 st5 = has5 ? stage_load(xin, oy0, r5, gc0_5, interior) : make_float4(0,0,0,0);

    const int  rA   = tid >> 2;
    const int  qqA  = tid & 3;
    const bool hasB = tid < 48;
    const int  rB   = 64 + (tid >> 2);

    #pragma unroll
    for (int t = 0; t < NT; ++t) {
        const int oyt = oy0 + t * TY;

        if (t) __syncthreads();          // prev tile's V reads of s must finish
        // commit staged regs -> LDS (waits vmcnt for this tile's loads)
        *reinterpret_cast<float4*>(&s[r0][c40 * 4]) = st0;
        *reinterpret_cast<float4*>(&s[r1][c41 * 4]) = st1;
        *reinterpret_cast<float4*>(&s[r2][c42 * 4]) = st2;
        *reinterpret_cast<float4*>(&s[r3][c43 * 4]) = st3;
        *reinterpret_cast<float4*>(&s[r4][c44 * 4]) = st4;
        if (has5) *reinterpret_cast<float4*>(&s[r5][c45 * 4]) = st5;

        // issue NEXT tile's loads now -> in flight under H+V compute (T14)
        if (t + 1 < NT) {
            const int oyn = oyt + TY;
            st0 = stage_load(xin, oyn, r0, gc0_0, interior);
            st1 = stage_load(xin, oyn, r1, gc0_1, interior);
            st2 = stage_load(xin, oyn, r2, gc0_2, interior);
            st3 = stage_load(xin, oyn, r3, gc0_3, interior);
            st4 = stage_load(xin, oyn, r4, gc0_4, interior);
            if (has5) st5 = stage_load(xin, oyn, r5, gc0_5, interior);
        }
        __syncthreads();

        // H pass: all reads, one barrier, all writes (in place, disjoint dests)
        float acc[16], acc2[16];
        h_read_compute(s, g, rA, qqA, acc);
        if (hasB) h_read_compute(s, g, rB, qqA, acc2);
        __syncthreads();
        h_write(s, rA, qqA, acc);
        if (hasB) h_write(s, rB, qqA, acc2);
        __syncthreads();

        // V pass: 128 tasks, 8 rows x 4 cols (20 reads / 32 outputs)
        if (tid < 128) {
            int q  = tid & 15;
            int rg = tid >> 4;
            int c  = 8 + 4 * q;
            int rb = rg * 8;

            float4 vacc[8];
            #pragma unroll
            for (int ii = 0; ii < 8; ++ii) vacc[ii] = make_float4(0, 0, 0, 0);

            #pragma unroll
            for (int i = 0; i < 20; ++i) {
                float4 v = *reinterpret_cast<const float4*>(&s[rb + i][c]);
                #pragma unroll
                for (int ii = 0; ii < 8; ++ii) {
                    int j = i - ii;
                    if (j >= 0 && j < KS) {
                        vacc[ii].x += g[j] * v.x;
                        vacc[ii].y += g[j] * v.y;
                        vacc[ii].z += g[j] * v.z;
                        vacc[ii].w += g[j] * v.w;
                    }
                }
            }

            #pragma unroll
            for (int ii = 0; ii < 8; ++ii)
                *reinterpret_cast<float4*>(o + (size_t)(oyt + rb + ii) * IMG_W + ox + 4 * q) = vacc[ii];
        }
    }
}

extern "C" void kernel_launch(void* const* d_in, const int* in_sizes, int n_in,
                              void* d_out, int out_size, void* d_ws, size_t ws_size,
                              hipStream_t stream) {
    const float* x   = (const float*)d_in[0];
    const float* k2d = (const float*)d_in[1];
    float*       out = (float*)d_out;

    dim3 grid(IMG_W / TX, IMG_H / (TY * NT), 32);  // 16 x 4 x 32 = 2048 blocks
    gauss_blur_fused<<<grid, 256, 0, stream>>>(x, k2d, out);
}

// Round 9
// 76.640 us; speedup vs baseline: 1.4246x; 1.4246x over previous
//
#include <hip/hip_runtime.h>

#define KS   13
#define HALF 6
#define TX   64
#define TY   32          // half-height tiles: 14.8 KB LDS -> ~8 blocks/CU resident
#define S_H  (TY + 12)   // 44
#define S_P  84          // pitch (floats): rows shift 21 granule-slots -> even spread
#define NG   20          // staged float4 granules/row (80 floats: 8 halo + 64 + 8)
#define NSTG (S_H * NG)  // 880 staging tasks
#define NH   (S_H * 4)   // 176 H tasks (16 outputs each)
#define IMG_H 1024
#define IMG_W 1024

__device__ __forceinline__ int reflect_idx(int i, int n) {
    if (i < 0) i = -i;
    if (i >= n) i = 2 * n - 2 - i;
    return i;
}

// H task (r, qq): outputs rel cols 16qq..16qq+15 from staged floats 16qq+2..16qq+29.
__device__ __forceinline__ void h_read_compute(const float (*s)[S_P], const float* g,
                                               int r, int qq, float* acc) {
    const int base = 16 * qq;
    float w[32];
    #pragma unroll
    for (int k = 0; k < 8; ++k) {
        float4 v = *reinterpret_cast<const float4*>(&s[r][base + 4 * k]);
        w[4*k+0] = v.x; w[4*k+1] = v.y; w[4*k+2] = v.z; w[4*k+3] = v.w;
    }
    #pragma unroll
    for (int u = 0; u < 16; ++u) acc[u] = 0.0f;
    #pragma unroll
    for (int j = 0; j < KS; ++j) {
        #pragma unroll
        for (int u = 0; u < 16; ++u)
            acc[u] += g[j] * w[u + 2 + j];
    }
}

__device__ __forceinline__ void h_write(float (*s)[S_P], int r, int qq, const float* acc) {
    const int base = 8 + 16 * qq;   // H row r -> s[r][8..71]
    #pragma unroll
    for (int k = 0; k < 4; ++k)
        *reinterpret_cast<float4*>(&s[r][base + 4 * k]) =
            make_float4(acc[4*k], acc[4*k+1], acc[4*k+2], acc[4*k+3]);
}

// No min-waves bound: (256,6) capped VGPRs at 40 -> 543 MB scratch spill (R2).
// No cross-tile register prefetch: R8's 6 live float4 -> VGPR 136 -> occupancy 11%.
__global__ __launch_bounds__(256) void gauss_blur_fused(
    const float* __restrict__ x, const float* __restrict__ k2d,
    float* __restrict__ out)
{
    __shared__ float s[S_H][S_P];   // 44*84*4 = 14784 B

    const int tid = threadIdx.x;
    const int bx  = blockIdx.x;
    const int ox  = bx * TX;
    const int oy  = blockIdx.y * TY;
    const int img = blockIdx.z;

    const float* xin = x + (size_t)img * IMG_H * IMG_W;
    float*       o   = out + (size_t)img * IMG_H * IMG_W;

    // per-thread 1D taps: k2d = outer(g,g), g[i] = k2d[i][6]/sqrt(k2d[6][6])
    float g[KS];
    {
        float c   = k2d[HALF * KS + HALF];
        float inv = 1.0f / sqrtf(c);
        #pragma unroll
        for (int j = 0; j < KS; ++j) g[j] = k2d[j * KS + HALF] * inv;
    }

    const bool interior = (bx > 0) && (bx < (IMG_W / TX) - 1);

    // ---- Stage: global -> s, coalesced float4. s[r][i] = x[refl(oy+r-6)][ox-8+i] ----
    #pragma unroll
    for (int t = 0; t < 4; ++t) {
        int idx = tid + t * 256;
        if (idx < NSTG) {
            int r   = idx / NG;
            int c4  = idx - r * NG;
            int gr  = reflect_idx(oy + r - HALF, IMG_H);
            const float* row = xin + (size_t)gr * IMG_W;
            int gc0 = ox - 8 + c4 * 4;
            float4 v;
            if (interior) {
                v = *reinterpret_cast<const float4*>(row + gc0);
            } else {
                v.x = row[reflect_idx(gc0 + 0, IMG_W)];
                v.y = row[reflect_idx(gc0 + 1, IMG_W)];
                v.z = row[reflect_idx(gc0 + 2, IMG_W)];
                v.w = row[reflect_idx(gc0 + 3, IMG_W)];
            }
            *reinterpret_cast<float4*>(&s[r][c4 * 4]) = v;
        }
    }
    __syncthreads();

    // ---- H pass: 176 tasks, 16 outputs each. ALL reads, one barrier, ALL writes
    // (in place; dests disjoint from any thread's pending reads only via barrier).
    {
        const bool hasH = tid < NH;
        const int  r    = tid >> 2;
        const int  qq   = tid & 3;
        float acc[16];
        if (hasH) h_read_compute(s, g, r, qq, acc);
        __syncthreads();
        if (hasH) h_write(s, r, qq, acc);
        __syncthreads();
    }

    // ---- V pass: 128 tasks, 4 rows x 4 cols each (16 reads / 16 outputs) ----
    if (tid < 128) {
        int q  = tid & 15;          // col granule
        int rg = tid >> 4;          // row group 0..7
        int c  = 8 + 4 * q;
        int rb = rg * 4;

        float4 vacc[4];
        #pragma unroll
        for (int ii = 0; ii < 4; ++ii) vacc[ii] = make_float4(0, 0, 0, 0);

        #pragma unroll
        for (int i = 0; i < KS + 3; ++i) {   // staged rows rb .. rb+15
            float4 v = *reinterpret_cast<const float4*>(&s[rb + i][c]);
            #pragma unroll
            for (int ii = 0; ii < 4; ++ii) {
                int j = i - ii;
                if (j >= 0 && j < KS) {
                    vacc[ii].x += g[j] * v.x;
                    vacc[ii].y += g[j] * v.y;
                    vacc[ii].z += g[j] * v.z;
                    vacc[ii].w += g[j] * v.w;
                }
            }
        }

        #pragma unroll
        for (int ii = 0; ii < 4; ++ii)
            *reinterpret_cast<float4*>(o + (size_t)(oy + rb + ii) * IMG_W + ox + 4 * q) = vacc[ii];
    }
}

extern "C" void kernel_launch(void* const* d_in, const int* in_sizes, int n_in,
                              void* d_out, int out_size, void* d_ws, size_t ws_size,
                              hipStream_t stream) {
    const float* x   = (const float*)d_in[0];
    const float* k2d = (const float*)d_in[1];
    float*       out = (float*)d_out;

    dim3 grid(IMG_W / TX, IMG_H / TY, 32);  // 16 x 32 x 32 = 16384 blocks
    gauss_blur_fused<<<grid, 256, 0, stream>>>(x, k2d, out);
}

// Round 10
// 62.040 us; speedup vs baseline: 1.7599x; 1.2353x over previous
//
#include <hip/hip_runtime.h>

#define KS    13
#define HALF  6
#define TY    32              // output rows per strip
#define NITER (TY + 12)       // 44 bodies: 12 prologue (fill window) + 32 output rows
#define IMG_H 1024
#define IMG_W 1024

__device__ __forceinline__ int reflect_idx(int i, int n) {
    if (i < 0) i = -i;
    if (i >= n) i = 2 * n - 2 - i;
    return i;
}

struct Ctx {
    const float* xin;
    float*       o;
    float        g[KS];
    int          t;        // thread's column granule: cols 4t..4t+3
    int          r0;       // strip's first output row
    bool         interior; // 2 <= t <= 253 : LDS window read needs no column reflect
};

// Body n (= outer*13 + U): commits raw input row (r0+n-6) to LDS, H-filters it into
// window slot U, then (n>=12) V-filters the window -> output row r0+n-12.
// All window indices are compile-time constants (U literal) -> registers, no scratch.
template<int U>
__device__ __forceinline__ void body(int outer, const Ctx& cx, float (*s)[IMG_W],
                                     float4 (&w)[KS], float4& cur)
{
    const int n = outer * 13 + U;
    if (n >= NITER) return;                 // block-uniform guard (barrier-safe)
    const int buf = n & 1;

    // issue next raw-row load early: in flight under H+V compute (T14, 8 VGPR)
    float4 nxt = cur;
    if (n + 1 < NITER) {
        const int rr = reflect_idx(cx.r0 + n - 5, IMG_H);
        nxt = *reinterpret_cast<const float4*>(cx.xin + (size_t)rr * IMG_W + 4 * cx.t);
    }

    // commit current raw row to ping-pong LDS; ONE barrier/row is WAR-safe:
    // body n+2 re-writes s[buf] only after barrier n+1, which follows body n's reads.
    *reinterpret_cast<float4*>(&s[buf][4 * cx.t]) = cur;
    __syncthreads();

    // 20-float horizontal window (granules 4t-8 .. 4t+8); edge threads reflect
    float f[20];
    if (cx.interior) {
        #pragma unroll
        for (int k = 0; k < 5; ++k) {
            float4 v = *reinterpret_cast<const float4*>(&s[buf][4 * cx.t - 8 + 4 * k]);
            f[4*k+0] = v.x; f[4*k+1] = v.y; f[4*k+2] = v.z; f[4*k+3] = v.w;
        }
    } else {
        #pragma unroll
        for (int k = 0; k < 20; ++k)
            f[k] = s[buf][reflect_idx(4 * cx.t - 8 + k, IMG_W)];
    }

    // H: 13 taps x 4 columns
    float4 h = make_float4(0.f, 0.f, 0.f, 0.f);
    #pragma unroll
    for (int j = 0; j < KS; ++j) {
        h.x += cx.g[j] * f[2 + j];
        h.y += cx.g[j] * f[3 + j];
        h.z += cx.g[j] * f[4 + j];
        h.w += cx.g[j] * f[5 + j];
    }
    w[U % KS] = h;

    // V: 13 taps over the rolling window -> output row r0 + n - 12
    if (n >= 12) {
        float4 a = make_float4(0.f, 0.f, 0.f, 0.f);
        #pragma unroll
        for (int j = 0; j < KS; ++j) {
            const float4 v = w[(U + 1 + j) % KS];
            a.x += cx.g[j] * v.x;
            a.y += cx.g[j] * v.y;
            a.z += cx.g[j] * v.z;
            a.w += cx.g[j] * v.w;
        }
        *reinterpret_cast<float4*>(cx.o + (size_t)(cx.r0 + n - 12) * IMG_W + 4 * cx.t) = a;
    }
    cur = nxt;
}

// No launch-bounds min-waves (R2: VGPR cap 40 -> 543 MB spill). ~115 VGPR expected.
__global__ __launch_bounds__(256) void gauss_blur_stream(
    const float* __restrict__ x, const float* __restrict__ k2d,
    float* __restrict__ out)
{
    __shared__ float s[2][IMG_W];   // 8192 B ping-pong raw-row buffer

    Ctx cx;
    cx.t  = threadIdx.x;
    cx.r0 = blockIdx.x * TY;
    const int img = blockIdx.y;
    cx.xin = x + (size_t)img * IMG_H * IMG_W;
    cx.o   = out + (size_t)img * IMG_H * IMG_W;
    cx.interior = (cx.t >= 2) && (cx.t <= 253);

    // 1D taps: k2d = outer(g,g) exactly, g[i] = k2d[i][6]/sqrt(k2d[6][6])
    {
        float c   = k2d[HALF * KS + HALF];
        float inv = 1.0f / sqrtf(c);
        #pragma unroll
        for (int j = 0; j < KS; ++j) cx.g[j] = k2d[j * KS + HALF] * inv;
    }

    float4 w[KS];
    // preload raw row for body 0: input row r0 - 6 (reflected)
    float4 cur = *reinterpret_cast<const float4*>(
        cx.xin + (size_t)reflect_idx(cx.r0 - 6, IMG_H) * IMG_W + 4 * cx.t);

    for (int outer = 0; outer < (NITER + 12) / 13; ++outer) {
        body< 0>(outer, cx, s, w, cur);
        body< 1>(outer, cx, s, w, cur);
        body< 2>(outer, cx, s, w, cur);
        body< 3>(outer, cx, s, w, cur);
        body< 4>(outer, cx, s, w, cur);
        body< 5>(outer, cx, s, w, cur);
        body< 6>(outer, cx, s, w, cur);
        body< 7>(outer, cx, s, w, cur);
        body< 8>(outer, cx, s, w, cur);
        body< 9>(outer, cx, s, w, cur);
        body<10>(outer, cx, s, w, cur);
        body<11>(outer, cx, s, w, cur);
        body<12>(outer, cx, s, w, cur);
    }
}

extern "C" void kernel_launch(void* const* d_in, const int* in_sizes, int n_in,
                              void* d_out, int out_size, void* d_ws, size_t ws_size,
                              hipStream_t stream) {
    const float* x   = (const float*)d_in[0];
    const float* k2d = (const float*)d_in[1];
    float*       out = (float*)d_out;

    dim3 grid(IMG_H / TY, 32);   // 32 strips x 32 images = 1024 blocks (4/CU)
    gauss_blur_stream<<<grid, 256, 0, stream>>>(x, k2d, out);
}